// Round 1
// baseline (502.119 us; speedup 1.0000x reference)
//
#include <hip/hip_runtime.h>
#include <math.h>

// ETM forward. B=1024 S=512 V=50000 E=300 H=800 T=50.
// Pipeline: k0 zero accumulators -> k1 token compaction + x=bow@rho (gather)
// -> k4 betaU=exp(alpha@rho^T) (V x T layout) + topic sums
// -> k2 h=relu(x@W1+b1) -> k3 mu/lv/theta/kl -> k6 recon + loss.
// bows never materialized (sparse: <=512 tokens/row).

#define Bn 1024
#define Sn 512
#define Vn 50000
#define En 300
#define Hn 800
#define Tn 50

__device__ __forceinline__ float waveReduceSum(float v) {
    #pragma unroll
    for (int off = 32; off > 0; off >>= 1) v += __shfl_xor(v, off, 64);
    return v;
}
__device__ __forceinline__ float waveReduceMax(float v) {
    #pragma unroll
    for (int off = 32; off > 0; off >>= 1) v = fmaxf(v, __shfl_xor(v, off, 64));
    return v;
}

__global__ void k0_init(float* topicsum, float* loss) {
    int t = threadIdx.x;
    if (t < Tn) topicsum[t] = 0.f;
    if (t == 63) *loss = 0.f;
}

// One block per batch row: compact valid tokens (order irrelevant: sums are
// commutative), count, and accumulate x[b,e] = sum(rho[tok,e]) / n.
__global__ __launch_bounds__(256) void k1_tokens_x(
        const int* __restrict__ ids, const float* __restrict__ rho,
        int* __restrict__ toks, int* __restrict__ counts,
        float* __restrict__ xbar) {
    __shared__ int sid[Sn];
    __shared__ int scount;
    const int b = blockIdx.x, tid = threadIdx.x;
    if (tid == 0) scount = 0;
    __syncthreads();
    for (int s = tid; s < Sn; s += 256) {
        int id = ids[b * Sn + s];
        if (id != 1 && id != 2) {
            int p = atomicAdd(&scount, 1);
            sid[p] = id;
        }
    }
    __syncthreads();
    const int n = scount;
    for (int s = tid; s < n; s += 256) toks[b * Sn + s] = sid[s];
    if (tid == 0) counts[b] = n;
    const float inv = 1.0f / (float)n;
    for (int e = tid; e < En; e += 256) {
        float acc = 0.f;
        for (int s = 0; s < n; ++s) {
            acc += rho[sid[s] * En + e];   // coalesced across lanes (contiguous e)
        }
        xbar[b * En + e] = acc * inv;
    }
}

// betaU[v,t] = exp(alpha[t,:]·rho[v,:]) and topicsum[t] += sum_v betaU[v,t].
// One v per thread; rho tile staged in LDS with +1 pad (conflict-free);
// alpha reads are wave-uniform (scalar path).
__global__ __launch_bounds__(256) void k4_beta(
        const float* __restrict__ rho, const float* __restrict__ alpha,
        float* __restrict__ betaU, float* __restrict__ topicsum) {
    __shared__ float tile[256 * 33];
    __shared__ float wsum[4][Tn];
    const int v0 = blockIdx.x * 256, tid = threadIdx.x;
    const int v = v0 + tid;
    const bool valid = v < Vn;
    float acc[Tn];
    #pragma unroll
    for (int t = 0; t < Tn; ++t) acc[t] = 0.f;

    for (int e0 = 0; e0 < En; e0 += 32) {
        const int ec = min(32, En - e0);
        __syncthreads();
        for (int idx = tid; idx < 256 * 32; idx += 256) {
            int vl = idx >> 5, e = idx & 31;
            int gv = v0 + vl;
            tile[vl * 33 + e] = (gv < Vn && e < ec) ? rho[gv * En + e0 + e] : 0.f;
        }
        __syncthreads();
        for (int e = 0; e < ec; ++e) {
            float r = tile[tid * 33 + e];
            #pragma unroll
            for (int t = 0; t < Tn; ++t)
                acc[t] += r * alpha[t * En + e0 + e];
        }
    }
    #pragma unroll
    for (int t = 0; t < Tn; ++t) acc[t] = valid ? expf(acc[t]) : 0.f;
    if (valid) {
        #pragma unroll
        for (int t = 0; t < Tn; ++t) betaU[v * Tn + t] = acc[t];
    }
    const int wave = tid >> 6, lane = tid & 63;
    #pragma unroll
    for (int t = 0; t < Tn; ++t) {
        float s = waveReduceSum(acc[t]);
        if (lane == 0) wsum[wave][t] = s;
    }
    __syncthreads();
    if (tid < Tn) {
        atomicAdd(&topicsum[tid], wsum[0][tid] + wsum[1][tid] + wsum[2][tid] + wsum[3][tid]);
    }
}

// h = relu(x @ W1 + b1): 8 batch rows per block, each thread owns 3-4 cols.
__global__ __launch_bounds__(256) void k2_h(
        const float* __restrict__ xbar, const float* __restrict__ W1,
        const float* __restrict__ b1, float* __restrict__ h) {
    const int BR = 8;
    __shared__ float xs[BR * En];
    const int b0 = blockIdx.x * BR, tid = threadIdx.x;
    for (int i = tid; i < BR * En; i += 256) xs[i] = xbar[b0 * En + i];
    __syncthreads();
    const int j0 = tid, j1 = tid + 256, j2 = tid + 512, j3 = tid + 768;
    const bool has3 = (j3 < Hn);
    float acc[BR][4];
    #pragma unroll
    for (int r = 0; r < BR; ++r) {
        acc[r][0] = b1[j0]; acc[r][1] = b1[j1]; acc[r][2] = b1[j2];
        acc[r][3] = has3 ? b1[j3] : 0.f;
    }
    for (int e = 0; e < En; ++e) {
        float w0 = W1[e * Hn + j0];
        float w1 = W1[e * Hn + j1];
        float w2 = W1[e * Hn + j2];
        float w3 = has3 ? W1[e * Hn + j3] : 0.f;
        #pragma unroll
        for (int r = 0; r < BR; ++r) {
            float xv = xs[r * En + e];
            acc[r][0] += xv * w0; acc[r][1] += xv * w1;
            acc[r][2] += xv * w2; acc[r][3] += xv * w3;
        }
    }
    #pragma unroll
    for (int r = 0; r < BR; ++r) {
        h[(b0 + r) * Hn + j0] = fmaxf(acc[r][0], 0.f);
        h[(b0 + r) * Hn + j1] = fmaxf(acc[r][1], 0.f);
        h[(b0 + r) * Hn + j2] = fmaxf(acc[r][2], 0.f);
        if (has3) h[(b0 + r) * Hn + j3] = fmaxf(acc[r][3], 0.f);
    }
}

// mu/lv = h@Wmu/Wlv + bias; theta = softmax(mu) over T; kl accumulated.
// 16 rows per block; each wave owns 4 rows; lane t<50 owns topic t.
__global__ __launch_bounds__(256) void k3_theta(
        const float* __restrict__ h, const float* __restrict__ Wmu,
        const float* __restrict__ bmu, const float* __restrict__ Wlv,
        const float* __restrict__ blv, float* __restrict__ theta,
        float* __restrict__ loss) {
    const int BR = 16;
    __shared__ float hs[BR * Hn];    // 51.2 KB
    const int b0 = blockIdx.x * BR, tid = threadIdx.x;
    for (int i = tid; i < BR * Hn; i += 256) hs[i] = h[b0 * Hn + i];
    __syncthreads();
    const int wave = tid >> 6, lane = tid & 63;
    const int t = (lane < Tn) ? lane : (Tn - 1);
    const bool act = (lane < Tn);
    float amu[4], alv[4];
    #pragma unroll
    for (int k = 0; k < 4; ++k) { amu[k] = bmu[t]; alv[k] = blv[t]; }
    const int rbase = wave * 4;
    for (int j = 0; j < Hn; ++j) {
        float wm = Wmu[j * Tn + t];
        float wl = Wlv[j * Tn + t];
        #pragma unroll
        for (int k = 0; k < 4; ++k) {
            float hv = hs[(rbase + k) * Hn + j];
            amu[k] += hv * wm;
            alv[k] += hv * wl;
        }
    }
    float klacc = 0.f;
    #pragma unroll
    for (int k = 0; k < 4; ++k) {
        float mu = amu[k], lv = alv[k];
        float m = waveReduceMax(act ? mu : -1e30f);
        float ex = act ? expf(mu - m) : 0.f;
        float ssum = waveReduceSum(ex);
        if (act) theta[(b0 + rbase + k) * Tn + lane] = ex / ssum;
        klacc += waveReduceSum(act ? (1.f + lv - mu * mu - expf(lv)) : 0.f);
    }
    if (lane == 0) atomicAdd(loss, -0.5f * klacc * (1.0f / (float)Bn));
}

// recon[b] = -sum_tokens log( sum_t (theta[b,t]/Z[t]) * betaU[tok,t] + 1e-5 )
// w[] premultiplied into 50 registers; betaU row is a contiguous 200B gather.
__global__ __launch_bounds__(256) void k6_recon(
        const int* __restrict__ toks, const int* __restrict__ counts,
        const float* __restrict__ theta, const float* __restrict__ topicsum,
        const float* __restrict__ betaU, float* __restrict__ loss) {
    __shared__ float sw[Tn];
    __shared__ float swred[4];
    const int b = blockIdx.x, tid = threadIdx.x;
    if (tid < Tn) sw[tid] = theta[b * Tn + tid] / topicsum[tid];
    __syncthreads();
    float wr[Tn];
    #pragma unroll
    for (int t = 0; t < Tn; ++t) wr[t] = sw[t];
    const int n = counts[b];
    float lsum = 0.f;
    for (int i = tid; i < n; i += 256) {
        int v = toks[b * Sn + i];
        const float* row = betaU + v * Tn;   // 8B-aligned (v*200 bytes)
        float dot = 0.f;
        #pragma unroll
        for (int t = 0; t < Tn; t += 2) {
            float2 p = *(const float2*)(row + t);
            dot += wr[t] * p.x + wr[t + 1] * p.y;
        }
        lsum += logf(dot + 1e-5f);
    }
    float s = waveReduceSum(lsum);
    const int wave = tid >> 6, lane = tid & 63;
    if (lane == 0) swred[wave] = s;
    __syncthreads();
    if (tid == 0) {
        float tot = swred[0] + swred[1] + swred[2] + swred[3];
        atomicAdd(loss, -tot * (1.0f / (float)Bn));
    }
}

extern "C" void kernel_launch(void* const* d_in, const int* in_sizes, int n_in,
                              void* d_out, int out_size, void* d_ws, size_t ws_size,
                              hipStream_t stream) {
    const int*   ids   = (const int*)d_in[0];
    const float* rho   = (const float*)d_in[1];
    const float* alpha = (const float*)d_in[2];
    const float* W1    = (const float*)d_in[3];
    const float* b1    = (const float*)d_in[4];
    const float* Wmu   = (const float*)d_in[5];
    const float* bmu   = (const float*)d_in[6];
    const float* Wlv   = (const float*)d_in[7];
    const float* blv   = (const float*)d_in[8];

    float* theta = (float*)d_out;            // [B, T]
    float* loss  = theta + Bn * Tn;          // scalar at d_out[51200]

    float* ws       = (float*)d_ws;
    float* topicsum = ws;                        // 64 floats (50 used)
    int*   counts   = (int*)(ws + 64);           // B ints
    int*   toks     = (int*)(ws + 64 + Bn);      // B*S ints
    float* xbar     = ws + 64 + Bn + Bn * Sn;    // B*E
    float* hbuf     = xbar + Bn * En;            // B*H
    float* betaU    = hbuf + Bn * Hn;            // V*T (offset even -> float2 ok)

    k0_init<<<1, 64, 0, stream>>>(topicsum, loss);
    k1_tokens_x<<<Bn, 256, 0, stream>>>(ids, rho, toks, counts, xbar);
    k4_beta<<<(Vn + 255) / 256, 256, 0, stream>>>(rho, alpha, betaU, topicsum);
    k2_h<<<Bn / 8, 256, 0, stream>>>(xbar, W1, b1, hbuf);
    k3_theta<<<Bn / 16, 256, 0, stream>>>(hbuf, Wmu, bmu, Wlv, blv, theta, loss);
    k6_recon<<<Bn, 256, 0, stream>>>(toks, counts, theta, topicsum, betaU, loss);
}

// Round 2
// 464.189 us; speedup vs baseline: 1.0817x; 1.0817x over previous
//
#include <hip/hip_runtime.h>
#include <math.h>

// ETM forward. B=1024 S=512 V=50000 E=300 H=800 T=50.
// Pipeline: k0 zero accumulators + transpose alpha->aT[e][t] (pad 64)
// -> k1 token compaction + x=bow@rho (gather)
// -> k4 betaU=exp(alpha@rho^T) (V x T layout, T split 2-way) + topic sums
// -> k2 h=relu(x@W1+b1) -> k3 mu/lv/theta/kl -> k6 recon + loss.
// bows never materialized (sparse: <=512 tokens/row).

#define Bn 1024
#define Sn 512
#define Vn 50000
#define En 300
#define Hn 800
#define Tn 50
#define TSPLIT 2
#define Tc (Tn / TSPLIT)   // 25 topics per k4 y-slice

__device__ __forceinline__ float waveReduceSum(float v) {
    #pragma unroll
    for (int off = 32; off > 0; off >>= 1) v += __shfl_xor(v, off, 64);
    return v;
}
__device__ __forceinline__ float waveReduceMax(float v) {
    #pragma unroll
    for (int off = 32; off > 0; off >>= 1) v = fmaxf(v, __shfl_xor(v, off, 64));
    return v;
}

// Zero accumulators + transpose alpha[t][e] -> aT[e*64 + t] (row pad 64 for
// aligned contiguous scalar loads in k4).
__global__ __launch_bounds__(256) void k0_init(
        const float* __restrict__ alpha, float* __restrict__ aT,
        float* __restrict__ topicsum, float* __restrict__ loss) {
    const int gid = blockIdx.x * 256 + threadIdx.x;
    if (blockIdx.x == 0) {
        if (threadIdx.x < Tn) topicsum[threadIdx.x] = 0.f;
        if (threadIdx.x == 63) *loss = 0.f;
    }
    if (gid < Tn * En) {
        int t = gid / En, e = gid - t * En;    // consecutive gid -> consecutive e
        aT[e * 64 + t] = alpha[t * En + e];
    }
}

// One block per batch row: compact valid tokens (order irrelevant: sums are
// commutative), count, and accumulate x[b,e] = sum(rho[tok,e]) / n.
__global__ __launch_bounds__(256) void k1_tokens_x(
        const int* __restrict__ ids, const float* __restrict__ rho,
        int* __restrict__ toks, int* __restrict__ counts,
        float* __restrict__ xbar) {
    __shared__ int sid[Sn];
    __shared__ int scount;
    const int b = blockIdx.x, tid = threadIdx.x;
    if (tid == 0) scount = 0;
    __syncthreads();
    for (int s = tid; s < Sn; s += 256) {
        int id = ids[b * Sn + s];
        if (id != 1 && id != 2) {
            int p = atomicAdd(&scount, 1);
            sid[p] = id;
        }
    }
    __syncthreads();
    const int n = scount;
    for (int s = tid; s < n; s += 256) toks[b * Sn + s] = sid[s];
    if (tid == 0) counts[b] = n;
    const float inv = 1.0f / (float)n;
    for (int e = tid; e < En; e += 256) {
        float acc = 0.f;
        for (int s = 0; s < n; ++s) {
            acc += rho[sid[s] * En + e];   // coalesced across lanes (contiguous e)
        }
        xbar[b * En + e] = acc * inv;
    }
}

// betaU[v,t] = exp(sum_e rho[v,e]*aT[e,t]); topicsum[t] += sum_v betaU[v,t].
// One v per thread; T split across blockIdx.y (25 acc regs each).
// aT reads are wave-uniform + contiguous -> wide s_load, SGPR operand FMAs.
__global__ __launch_bounds__(256) void k4_beta(
        const float* __restrict__ rho, const float* __restrict__ aT,
        float* __restrict__ betaU, float* __restrict__ topicsum) {
    __shared__ float tile[256 * 33];
    __shared__ float wsum[4][Tc];
    const int v0 = blockIdx.x * 256, tid = threadIdx.x;
    const int t0 = blockIdx.y * Tc;
    const int v = v0 + tid;
    const bool valid = v < Vn;
    float acc[Tc];
    #pragma unroll
    for (int t = 0; t < Tc; ++t) acc[t] = 0.f;

    for (int e0 = 0; e0 < En; e0 += 32) {
        const int ec = min(32, En - e0);
        __syncthreads();
        for (int idx = tid; idx < 256 * 32; idx += 256) {
            int vl = idx >> 5, e = idx & 31;
            int gv = v0 + vl;
            tile[vl * 33 + e] = (gv < Vn && e < ec) ? rho[gv * En + e0 + e] : 0.f;
        }
        __syncthreads();
        for (int e = 0; e < ec; ++e) {
            float r = tile[tid * 33 + e];
            const float* __restrict__ a = aT + (e0 + e) * 64 + t0;  // uniform
            #pragma unroll
            for (int t = 0; t < Tc; ++t)
                acc[t] = fmaf(r, a[t], acc[t]);
        }
    }
    #pragma unroll
    for (int t = 0; t < Tc; ++t) acc[t] = valid ? expf(acc[t]) : 0.f;
    if (valid) {
        #pragma unroll
        for (int t = 0; t < Tc; ++t) betaU[v * Tn + t0 + t] = acc[t];
    }
    const int wave = tid >> 6, lane = tid & 63;
    #pragma unroll
    for (int t = 0; t < Tc; ++t) {
        float s = waveReduceSum(acc[t]);
        if (lane == 0) wsum[wave][t] = s;
    }
    __syncthreads();
    if (tid < Tc) {
        atomicAdd(&topicsum[t0 + tid],
                  wsum[0][tid] + wsum[1][tid] + wsum[2][tid] + wsum[3][tid]);
    }
}

// h = relu(x @ W1 + b1): 8 batch rows per block, each thread owns 3-4 cols.
__global__ __launch_bounds__(256) void k2_h(
        const float* __restrict__ xbar, const float* __restrict__ W1,
        const float* __restrict__ b1, float* __restrict__ h) {
    const int BR = 8;
    __shared__ float xs[BR * En];
    const int b0 = blockIdx.x * BR, tid = threadIdx.x;
    for (int i = tid; i < BR * En; i += 256) xs[i] = xbar[b0 * En + i];
    __syncthreads();
    const int j0 = tid, j1 = tid + 256, j2 = tid + 512, j3 = tid + 768;
    const bool has3 = (j3 < Hn);
    float acc[BR][4];
    #pragma unroll
    for (int r = 0; r < BR; ++r) {
        acc[r][0] = b1[j0]; acc[r][1] = b1[j1]; acc[r][2] = b1[j2];
        acc[r][3] = has3 ? b1[j3] : 0.f;
    }
    for (int e = 0; e < En; ++e) {
        float w0 = W1[e * Hn + j0];
        float w1 = W1[e * Hn + j1];
        float w2 = W1[e * Hn + j2];
        float w3 = has3 ? W1[e * Hn + j3] : 0.f;
        #pragma unroll
        for (int r = 0; r < BR; ++r) {
            float xv = xs[r * En + e];
            acc[r][0] += xv * w0; acc[r][1] += xv * w1;
            acc[r][2] += xv * w2; acc[r][3] += xv * w3;
        }
    }
    #pragma unroll
    for (int r = 0; r < BR; ++r) {
        h[(b0 + r) * Hn + j0] = fmaxf(acc[r][0], 0.f);
        h[(b0 + r) * Hn + j1] = fmaxf(acc[r][1], 0.f);
        h[(b0 + r) * Hn + j2] = fmaxf(acc[r][2], 0.f);
        if (has3) h[(b0 + r) * Hn + j3] = fmaxf(acc[r][3], 0.f);
    }
}

// mu/lv = h@Wmu/Wlv + bias; theta = softmax(mu) over T; kl accumulated.
// 16 rows per block; each wave owns 4 rows; lane t<50 owns topic t.
__global__ __launch_bounds__(256) void k3_theta(
        const float* __restrict__ h, const float* __restrict__ Wmu,
        const float* __restrict__ bmu, const float* __restrict__ Wlv,
        const float* __restrict__ blv, float* __restrict__ theta,
        float* __restrict__ loss) {
    const int BR = 16;
    __shared__ float hs[BR * Hn];    // 51.2 KB
    const int b0 = blockIdx.x * BR, tid = threadIdx.x;
    for (int i = tid; i < BR * Hn; i += 256) hs[i] = h[b0 * Hn + i];
    __syncthreads();
    const int wave = tid >> 6, lane = tid & 63;
    const int t = (lane < Tn) ? lane : (Tn - 1);
    const bool act = (lane < Tn);
    float amu[4], alv[4];
    #pragma unroll
    for (int k = 0; k < 4; ++k) { amu[k] = bmu[t]; alv[k] = blv[t]; }
    const int rbase = wave * 4;
    for (int j = 0; j < Hn; ++j) {
        float wm = Wmu[j * Tn + t];
        float wl = Wlv[j * Tn + t];
        #pragma unroll
        for (int k = 0; k < 4; ++k) {
            float hv = hs[(rbase + k) * Hn + j];
            amu[k] += hv * wm;
            alv[k] += hv * wl;
        }
    }
    float klacc = 0.f;
    #pragma unroll
    for (int k = 0; k < 4; ++k) {
        float mu = amu[k], lv = alv[k];
        float m = waveReduceMax(act ? mu : -1e30f);
        float ex = act ? expf(mu - m) : 0.f;
        float ssum = waveReduceSum(ex);
        if (act) theta[(b0 + rbase + k) * Tn + lane] = ex / ssum;
        klacc += waveReduceSum(act ? (1.f + lv - mu * mu - expf(lv)) : 0.f);
    }
    if (lane == 0) atomicAdd(loss, -0.5f * klacc * (1.0f / (float)Bn));
}

// recon[b] = -sum_tokens log( sum_t (theta[b,t]/Z[t]) * betaU[tok,t] + 1e-5 )
// w[] premultiplied into 50 registers; betaU row is a contiguous 200B gather.
__global__ __launch_bounds__(256) void k6_recon(
        const int* __restrict__ toks, const int* __restrict__ counts,
        const float* __restrict__ theta, const float* __restrict__ topicsum,
        const float* __restrict__ betaU, float* __restrict__ loss) {
    __shared__ float sw[Tn];
    __shared__ float swred[4];
    const int b = blockIdx.x, tid = threadIdx.x;
    if (tid < Tn) sw[tid] = theta[b * Tn + tid] / topicsum[tid];
    __syncthreads();
    float wr[Tn];
    #pragma unroll
    for (int t = 0; t < Tn; ++t) wr[t] = sw[t];
    const int n = counts[b];
    float lsum = 0.f;
    for (int i = tid; i < n; i += 256) {
        int v = toks[b * Sn + i];
        const float* row = betaU + v * Tn;   // 8B-aligned (v*200 bytes)
        float dot = 0.f;
        #pragma unroll
        for (int t = 0; t < Tn; t += 2) {
            float2 p = *(const float2*)(row + t);
            dot += wr[t] * p.x + wr[t + 1] * p.y;
        }
        lsum += logf(dot + 1e-5f);
    }
    float s = waveReduceSum(lsum);
    const int wave = tid >> 6, lane = tid & 63;
    if (lane == 0) swred[wave] = s;
    __syncthreads();
    if (tid == 0) {
        float tot = swred[0] + swred[1] + swred[2] + swred[3];
        atomicAdd(loss, -tot * (1.0f / (float)Bn));
    }
}

extern "C" void kernel_launch(void* const* d_in, const int* in_sizes, int n_in,
                              void* d_out, int out_size, void* d_ws, size_t ws_size,
                              hipStream_t stream) {
    const int*   ids   = (const int*)d_in[0];
    const float* rho   = (const float*)d_in[1];
    const float* alpha = (const float*)d_in[2];
    const float* W1    = (const float*)d_in[3];
    const float* b1    = (const float*)d_in[4];
    const float* Wmu   = (const float*)d_in[5];
    const float* bmu   = (const float*)d_in[6];
    const float* Wlv   = (const float*)d_in[7];
    const float* blv   = (const float*)d_in[8];

    float* theta = (float*)d_out;            // [B, T]
    float* loss  = theta + Bn * Tn;          // scalar at d_out[51200]

    float* ws       = (float*)d_ws;
    float* topicsum = ws;                        // 64 floats (50 used)
    float* aT       = ws + 64;                   // E*64 transposed alpha
    int*   counts   = (int*)(aT + En * 64);      // B ints
    int*   toks     = (int*)(aT + En * 64 + Bn); // B*S ints
    float* xbar     = aT + En * 64 + Bn + Bn * Sn;   // B*E
    float* hbuf     = xbar + Bn * En;            // B*H
    float* betaU    = hbuf + Bn * Hn;            // V*T (offset even -> float2 ok)

    k0_init<<<(Tn * En + 255) / 256, 256, 0, stream>>>(alpha, aT, topicsum, loss);
    k1_tokens_x<<<Bn, 256, 0, stream>>>(ids, rho, toks, counts, xbar);
    k4_beta<<<dim3((Vn + 255) / 256, TSPLIT), 256, 0, stream>>>(rho, aT, betaU, topicsum);
    k2_h<<<Bn / 8, 256, 0, stream>>>(xbar, W1, b1, hbuf);
    k3_theta<<<Bn / 16, 256, 0, stream>>>(hbuf, Wmu, bmu, Wlv, blv, theta, loss);
    k6_recon<<<Bn, 256, 0, stream>>>(toks, counts, theta, topicsum, betaU, loss);
}

// Round 3
// 419.131 us; speedup vs baseline: 1.1980x; 1.1075x over previous
//
#include <hip/hip_runtime.h>
#include <math.h>

// ETM forward. B=1024 S=512 V=50000 E=300 H=800 T=50.
// Pipeline: k0 zero accumulators + transpose alpha->aT[e][t] (pad 64)
// -> k1 token compaction + x=bow@rho (gather)
// -> k4 betaU=exp(alpha@rho^T) register-tiled (2v x 10t per thread)
// -> k2 h=relu(x@W1+b1) -> k3 mu/lv/theta/kl -> k6 recon + loss.
// bows never materialized (sparse: <=512 tokens/row).

#define Bn 1024
#define Sn 512
#define Vn 50000
#define En 300
#define Hn 800
#define Tn 50
#define TSPLIT 5
#define Tc (Tn / TSPLIT)   // 10 topics per k4 y-slice
#define VT 512             // v-tile per block (2 per thread)
#define EC 20              // e-chunk (300 = 15 * 20)

__device__ __forceinline__ float waveReduceSum(float v) {
    #pragma unroll
    for (int off = 32; off > 0; off >>= 1) v += __shfl_xor(v, off, 64);
    return v;
}
__device__ __forceinline__ float waveReduceMax(float v) {
    #pragma unroll
    for (int off = 32; off > 0; off >>= 1) v = fmaxf(v, __shfl_xor(v, off, 64));
    return v;
}

// Zero accumulators + transpose alpha[t][e] -> aT[e*64 + t] (row pad 64).
__global__ __launch_bounds__(256) void k0_init(
        const float* __restrict__ alpha, float* __restrict__ aT,
        float* __restrict__ topicsum, float* __restrict__ loss) {
    const int gid = blockIdx.x * 256 + threadIdx.x;
    if (blockIdx.x == 0) {
        if (threadIdx.x < Tn) topicsum[threadIdx.x] = 0.f;
        if (threadIdx.x == 63) *loss = 0.f;
    }
    if (gid < Tn * En) {
        int t = gid / En, e = gid - t * En;
        aT[e * 64 + t] = alpha[t * En + e];
    }
}

// One block per batch row: compact valid tokens, count, and accumulate
// x[b,e] = sum(rho[tok,e]) / n.
__global__ __launch_bounds__(256) void k1_tokens_x(
        const int* __restrict__ ids, const float* __restrict__ rho,
        int* __restrict__ toks, int* __restrict__ counts,
        float* __restrict__ xbar) {
    __shared__ int sid[Sn];
    __shared__ int scount;
    const int b = blockIdx.x, tid = threadIdx.x;
    if (tid == 0) scount = 0;
    __syncthreads();
    for (int s = tid; s < Sn; s += 256) {
        int id = ids[b * Sn + s];
        if (id != 1 && id != 2) {
            int p = atomicAdd(&scount, 1);
            sid[p] = id;
        }
    }
    __syncthreads();
    const int n = scount;
    for (int s = tid; s < n; s += 256) toks[b * Sn + s] = sid[s];
    if (tid == 0) counts[b] = n;
    const float inv = 1.0f / (float)n;
    for (int e = tid; e < En; e += 256) {
        float acc = 0.f;
        for (int s = 0; s < n; ++s) {
            acc += rho[sid[s] * En + e];   // coalesced across lanes
        }
        xbar[b * En + e] = acc * inv;
    }
}

// betaU[v,t] = exp(sum_e rho[v,e]*alpha[t,e]); topicsum[t] += sum_v betaU.
// Register-tiled: thread owns v0+tid and v0+256+tid, Tc=10 topics.
// rho staged [VT][EC pad 21] (odd stride -> conflict-free); alpha slice
// staged once [En][Tc pad 12] read as broadcast float4/float2.
__global__ __launch_bounds__(256) void k4_beta(
        const float* __restrict__ rho, const float* __restrict__ aT,
        float* __restrict__ betaU, float* __restrict__ topicsum) {
    __shared__ float tile[VT * (EC + 1)];    // 43008 B
    __shared__ float asl[En * 12];           // 14400 B
    __shared__ float wsum[4][Tc];
    const int v0 = blockIdx.x * VT, tid = threadIdx.x;
    const int t0 = blockIdx.y * Tc;

    // stage alpha slice: asl[e*12 + tt] = alpha[t0+tt][e]
    for (int idx = tid; idx < En * Tc; idx += 256) {
        int e = idx / Tc, tt = idx - e * Tc;
        asl[e * 12 + tt] = aT[e * 64 + t0 + tt];
    }

    float acc0[Tc], acc1[Tc];
    #pragma unroll
    for (int t = 0; t < Tc; ++t) { acc0[t] = 0.f; acc1[t] = 0.f; }

    const int va = v0 + tid;          // always < Vn (last tile: <= 49919)
    const int vb = v0 + 256 + tid;
    const bool valb = vb < Vn;

    for (int c = 0; c < En / EC; ++c) {
        const int e0 = c * EC;
        __syncthreads();
        // stage rho tile: VT rows x EC floats, float4 loads (16B aligned)
        for (int idx = tid; idx < VT * (EC / 4); idx += 256) {
            int vl = idx / (EC / 4), j = idx - vl * (EC / 4);
            int gv = v0 + vl;
            float4 r = make_float4(0.f, 0.f, 0.f, 0.f);
            if (gv < Vn) r = *(const float4*)(rho + (size_t)gv * En + e0 + 4 * j);
            float* dst = &tile[vl * (EC + 1) + 4 * j];
            dst[0] = r.x; dst[1] = r.y; dst[2] = r.z; dst[3] = r.w;
        }
        __syncthreads();
        #pragma unroll
        for (int e = 0; e < EC; ++e) {
            float r0 = tile[tid * (EC + 1) + e];
            float r1 = tile[(tid + 256) * (EC + 1) + e];
            const float* a = &asl[(e0 + e) * 12];
            float4 a0 = *(const float4*)(a);
            float4 a1 = *(const float4*)(a + 4);
            float2 a2 = *(const float2*)(a + 8);
            acc0[0] = fmaf(r0, a0.x, acc0[0]);  acc1[0] = fmaf(r1, a0.x, acc1[0]);
            acc0[1] = fmaf(r0, a0.y, acc0[1]);  acc1[1] = fmaf(r1, a0.y, acc1[1]);
            acc0[2] = fmaf(r0, a0.z, acc0[2]);  acc1[2] = fmaf(r1, a0.z, acc1[2]);
            acc0[3] = fmaf(r0, a0.w, acc0[3]);  acc1[3] = fmaf(r1, a0.w, acc1[3]);
            acc0[4] = fmaf(r0, a1.x, acc0[4]);  acc1[4] = fmaf(r1, a1.x, acc1[4]);
            acc0[5] = fmaf(r0, a1.y, acc0[5]);  acc1[5] = fmaf(r1, a1.y, acc1[5]);
            acc0[6] = fmaf(r0, a1.z, acc0[6]);  acc1[6] = fmaf(r1, a1.z, acc1[6]);
            acc0[7] = fmaf(r0, a1.w, acc0[7]);  acc1[7] = fmaf(r1, a1.w, acc1[7]);
            acc0[8] = fmaf(r0, a2.x, acc0[8]);  acc1[8] = fmaf(r1, a2.x, acc1[8]);
            acc0[9] = fmaf(r0, a2.y, acc0[9]);  acc1[9] = fmaf(r1, a2.y, acc1[9]);
        }
    }

    #pragma unroll
    for (int t = 0; t < Tc; ++t) {
        acc0[t] = expf(acc0[t]);
        acc1[t] = valb ? expf(acc1[t]) : 0.f;
    }
    // store betaU rows (float2: v*200 + t0*4 bytes, 8B aligned)
    #pragma unroll
    for (int t = 0; t < Tc; t += 2) {
        *(float2*)(betaU + (size_t)va * Tn + t0 + t) = make_float2(acc0[t], acc0[t + 1]);
    }
    if (valb) {
        #pragma unroll
        for (int t = 0; t < Tc; t += 2) {
            *(float2*)(betaU + (size_t)vb * Tn + t0 + t) = make_float2(acc1[t], acc1[t + 1]);
        }
    }
    const int wave = tid >> 6, lane = tid & 63;
    #pragma unroll
    for (int t = 0; t < Tc; ++t) {
        float s = waveReduceSum(acc0[t] + acc1[t]);
        if (lane == 0) wsum[wave][t] = s;
    }
    __syncthreads();
    if (tid < Tc) {
        atomicAdd(&topicsum[t0 + tid],
                  wsum[0][tid] + wsum[1][tid] + wsum[2][tid] + wsum[3][tid]);
    }
}

// h = relu(x @ W1 + b1): 8 batch rows per block, each thread owns 3-4 cols.
__global__ __launch_bounds__(256) void k2_h(
        const float* __restrict__ xbar, const float* __restrict__ W1,
        const float* __restrict__ b1, float* __restrict__ h) {
    const int BR = 8;
    __shared__ float xs[BR * En];
    const int b0 = blockIdx.x * BR, tid = threadIdx.x;
    for (int i = tid; i < BR * En; i += 256) xs[i] = xbar[b0 * En + i];
    __syncthreads();
    const int j0 = tid, j1 = tid + 256, j2 = tid + 512, j3 = tid + 768;
    const bool has3 = (j3 < Hn);
    float acc[BR][4];
    #pragma unroll
    for (int r = 0; r < BR; ++r) {
        acc[r][0] = b1[j0]; acc[r][1] = b1[j1]; acc[r][2] = b1[j2];
        acc[r][3] = has3 ? b1[j3] : 0.f;
    }
    for (int e = 0; e < En; ++e) {
        float w0 = W1[e * Hn + j0];
        float w1 = W1[e * Hn + j1];
        float w2 = W1[e * Hn + j2];
        float w3 = has3 ? W1[e * Hn + j3] : 0.f;
        #pragma unroll
        for (int r = 0; r < BR; ++r) {
            float xv = xs[r * En + e];
            acc[r][0] += xv * w0; acc[r][1] += xv * w1;
            acc[r][2] += xv * w2; acc[r][3] += xv * w3;
        }
    }
    #pragma unroll
    for (int r = 0; r < BR; ++r) {
        h[(b0 + r) * Hn + j0] = fmaxf(acc[r][0], 0.f);
        h[(b0 + r) * Hn + j1] = fmaxf(acc[r][1], 0.f);
        h[(b0 + r) * Hn + j2] = fmaxf(acc[r][2], 0.f);
        if (has3) h[(b0 + r) * Hn + j3] = fmaxf(acc[r][3], 0.f);
    }
}

// mu/lv = h@Wmu/Wlv + bias; theta = softmax(mu) over T; kl accumulated.
__global__ __launch_bounds__(256) void k3_theta(
        const float* __restrict__ h, const float* __restrict__ Wmu,
        const float* __restrict__ bmu, const float* __restrict__ Wlv,
        const float* __restrict__ blv, float* __restrict__ theta,
        float* __restrict__ loss) {
    const int BR = 16;
    __shared__ float hs[BR * Hn];    // 51.2 KB
    const int b0 = blockIdx.x * BR, tid = threadIdx.x;
    for (int i = tid; i < BR * Hn; i += 256) hs[i] = h[b0 * Hn + i];
    __syncthreads();
    const int wave = tid >> 6, lane = tid & 63;
    const int t = (lane < Tn) ? lane : (Tn - 1);
    const bool act = (lane < Tn);
    float amu[4], alv[4];
    #pragma unroll
    for (int k = 0; k < 4; ++k) { amu[k] = bmu[t]; alv[k] = blv[t]; }
    const int rbase = wave * 4;
    for (int j = 0; j < Hn; ++j) {
        float wm = Wmu[j * Tn + t];
        float wl = Wlv[j * Tn + t];
        #pragma unroll
        for (int k = 0; k < 4; ++k) {
            float hv = hs[(rbase + k) * Hn + j];
            amu[k] += hv * wm;
            alv[k] += hv * wl;
        }
    }
    float klacc = 0.f;
    #pragma unroll
    for (int k = 0; k < 4; ++k) {
        float mu = amu[k], lv = alv[k];
        float m = waveReduceMax(act ? mu : -1e30f);
        float ex = act ? expf(mu - m) : 0.f;
        float ssum = waveReduceSum(ex);
        if (act) theta[(b0 + rbase + k) * Tn + lane] = ex / ssum;
        klacc += waveReduceSum(act ? (1.f + lv - mu * mu - expf(lv)) : 0.f);
    }
    if (lane == 0) atomicAdd(loss, -0.5f * klacc * (1.0f / (float)Bn));
}

// recon[b] = -sum_tokens log( sum_t (theta[b,t]/Z[t]) * betaU[tok,t] + 1e-5 )
__global__ __launch_bounds__(256) void k6_recon(
        const int* __restrict__ toks, const int* __restrict__ counts,
        const float* __restrict__ theta, const float* __restrict__ topicsum,
        const float* __restrict__ betaU, float* __restrict__ loss) {
    __shared__ float sw[Tn];
    __shared__ float swred[4];
    const int b = blockIdx.x, tid = threadIdx.x;
    if (tid < Tn) sw[tid] = theta[b * Tn + tid] / topicsum[tid];
    __syncthreads();
    float wr[Tn];
    #pragma unroll
    for (int t = 0; t < Tn; ++t) wr[t] = sw[t];
    const int n = counts[b];
    float lsum = 0.f;
    for (int i = tid; i < n; i += 256) {
        int v = toks[b * Sn + i];
        const float* row = betaU + (size_t)v * Tn;
        float dot = 0.f;
        #pragma unroll
        for (int t = 0; t < Tn; t += 2) {
            float2 p = *(const float2*)(row + t);
            dot += wr[t] * p.x + wr[t + 1] * p.y;
        }
        lsum += logf(dot + 1e-5f);
    }
    float s = waveReduceSum(lsum);
    const int wave = tid >> 6, lane = tid & 63;
    if (lane == 0) swred[wave] = s;
    __syncthreads();
    if (tid == 0) {
        float tot = swred[0] + swred[1] + swred[2] + swred[3];
        atomicAdd(loss, -tot * (1.0f / (float)Bn));
    }
}

extern "C" void kernel_launch(void* const* d_in, const int* in_sizes, int n_in,
                              void* d_out, int out_size, void* d_ws, size_t ws_size,
                              hipStream_t stream) {
    const int*   ids   = (const int*)d_in[0];
    const float* rho   = (const float*)d_in[1];
    const float* alpha = (const float*)d_in[2];
    const float* W1    = (const float*)d_in[3];
    const float* b1    = (const float*)d_in[4];
    const float* Wmu   = (const float*)d_in[5];
    const float* bmu   = (const float*)d_in[6];
    const float* Wlv   = (const float*)d_in[7];
    const float* blv   = (const float*)d_in[8];

    float* theta = (float*)d_out;            // [B, T]
    float* loss  = theta + Bn * Tn;          // scalar at d_out[51200]

    float* ws       = (float*)d_ws;
    float* topicsum = ws;                        // 64 floats (50 used)
    float* aT       = ws + 64;                   // E*64 transposed alpha
    int*   counts   = (int*)(aT + En * 64);      // B ints
    int*   toks     = (int*)(aT + En * 64 + Bn); // B*S ints
    float* xbar     = aT + En * 64 + Bn + Bn * Sn;   // B*E
    float* hbuf     = xbar + Bn * En;            // B*H
    float* betaU    = hbuf + Bn * Hn;            // V*T (offset even -> float2 ok)

    k0_init<<<(Tn * En + 255) / 256, 256, 0, stream>>>(alpha, aT, topicsum, loss);
    k1_tokens_x<<<Bn, 256, 0, stream>>>(ids, rho, toks, counts, xbar);
    k4_beta<<<dim3((Vn + VT - 1) / VT, TSPLIT), 256, 0, stream>>>(rho, aT, betaU, topicsum);
    k2_h<<<Bn / 8, 256, 0, stream>>>(xbar, W1, b1, hbuf);
    k3_theta<<<Bn / 16, 256, 0, stream>>>(hbuf, Wmu, bmu, Wlv, blv, theta, loss);
    k6_recon<<<Bn, 256, 0, stream>>>(toks, counts, theta, topicsum, betaU, loss);
}